// Round 2
// baseline (434.733 us; speedup 1.0000x reference)
//
#include <hip/hip_runtime.h>

#define NROWS 8192
#define DIM 512
#define HID 1024
#define BN_EPS 1e-5f

typedef unsigned short ushort_t;
typedef __attribute__((ext_vector_type(8))) __bf16 bf16x8;
typedef __attribute__((ext_vector_type(4))) float f32x4;

union U4 {
    uint4 u;
    bf16x8 b;
    ushort_t s[8];
};

static __device__ __forceinline__ float b2f(ushort_t u) {
    union { float f; unsigned int i; } c;
    c.i = ((unsigned int)u) << 16;
    return c.f;
}

static __device__ __forceinline__ ushort_t f2b(float f) {
    union { float f; unsigned int i; } c;
    c.f = f;
    unsigned int i = c.i;
    unsigned int r = (i + 0x7FFFu + ((i >> 16) & 1u)) >> 16;
    return (ushort_t)r;
}

// ---------------------------------------------------------------------------
// 1) column-sum of h: hs[d] = sum_n h[n,d]   (hs pre-zeroed by memset)
// grid 64 x 256; each block covers 128 rows (64 iters x 2 row-subgroups).
__global__ void colsum_kernel(const float* __restrict__ h, float* __restrict__ hs) {
    int t = threadIdx.x;
    int col0 = (t & 127) * 4;
    int rsub = t >> 7;
    int row0 = blockIdx.x * 128;
    float acc[4] = {0.f, 0.f, 0.f, 0.f};
    for (int r = 0; r < 64; ++r) {
        int row = row0 + r * 2 + rsub;
        float4 v = *(const float4*)(h + row * DIM + col0);
        acc[0] += v.x; acc[1] += v.y; acc[2] += v.z; acc[3] += v.w;
    }
#pragma unroll
    for (int j = 0; j < 4; ++j) atomicAdd(&hs[col0 + j], acc[j]);
}

// ---------------------------------------------------------------------------
// 2) matvec: outv[col] = sum_k xin[k] * W[k*512+col] + scaleB * bvec[col]
// W is [512][512] fp32.  grid 16 x 256.
__global__ void matvec_kernel(const float* __restrict__ xin, const float* __restrict__ W,
                              const float* __restrict__ bvec, float scaleB,
                              float* __restrict__ outv) {
    __shared__ float red[8][32];
    int t = threadIdx.x;
    int col = blockIdx.x * 32 + (t & 31);
    int ks = t >> 5;
    float s = 0.f;
    for (int ki = 0; ki < 64; ++ki) {
        int k = ks * 64 + ki;
        s += xin[k] * W[k * 512 + col];
    }
    red[ks][t & 31] = s;
    __syncthreads();
    if (ks == 0) {
        float tot = scaleB * bvec[col];
#pragma unroll
        for (int r = 0; r < 8; ++r) tot += red[r][t & 31];
        outv[col] = tot;
    }
}

// ---------------------------------------------------------------------------
// 3) per-column constants: p = a1, q0 = t*a1 + c1, a2v, c2v.  1 block x 512.
__global__ void prep_const_kernel(const float* __restrict__ tvec,
                                  const float* g1, const float* b1,
                                  const float* m1, const float* v1,
                                  const float* g2, const float* b2,
                                  const float* m2, const float* v2,
                                  float* __restrict__ p, float* __restrict__ q0,
                                  float* __restrict__ a2v, float* __restrict__ c2v) {
    int d = threadIdx.x;
    float a1 = g1[d] * rsqrtf(v1[d] + BN_EPS);
    float c1 = b1[d] - m1[d] * a1;
    p[d] = a1;
    q0[d] = tvec[d] * a1 + c1;
    float a2 = g2[d] * rsqrtf(v2[d] + BN_EPS);
    a2v[d] = a2;
    c2v[d] = b2[d] - m2[d] * a2;
}

// ---------------------------------------------------------------------------
// 4) X1[n,d] = bf16(h[n,d]*p[d] + q0[d]).  grid 4096 x 256, 4 elems/thread.
__global__ void x1_kernel(const float* __restrict__ h, const float* __restrict__ p,
                          const float* __restrict__ q0, ushort_t* __restrict__ x1) {
    int idx = (blockIdx.x * blockDim.x + threadIdx.x) * 4;
    int d0 = idx & (DIM - 1);
    float4 hv = *(const float4*)(h + idx);
    ushort_t ov[4];
    ov[0] = f2b(hv.x * p[d0 + 0] + q0[d0 + 0]);
    ov[1] = f2b(hv.y * p[d0 + 1] + q0[d0 + 1]);
    ov[2] = f2b(hv.z * p[d0 + 2] + q0[d0 + 2]);
    ov[3] = f2b(hv.w * p[d0 + 3] + q0[d0 + 3]);
    *(uint2*)(x1 + idx) = *(uint2*)ov;
}

// ---------------------------------------------------------------------------
// 5) transpose fp32 [R][C] -> bf16 [C][R].  grid (C/32, R/32) x 256.
__global__ void transpose_kernel(const float* __restrict__ in, ushort_t* __restrict__ out,
                                 int R, int C) {
    __shared__ float tile[32][33];
    int tx = threadIdx.x & 31, ty = threadIdx.x >> 5;
    int bx = blockIdx.x * 32, by = blockIdx.y * 32;
#pragma unroll
    for (int i = 0; i < 32; i += 8)
        tile[ty + i][tx] = in[(by + ty + i) * C + bx + tx];
    __syncthreads();
#pragma unroll
    for (int i = 0; i < 32; i += 8)
        out[(bx + ty + i) * R + by + tx] = f2b(tile[tx][ty + i]);
}

// ---------------------------------------------------------------------------
// 6) GEMM:  C[M][N] = act(A[M][K] @ B + bias),  B given transposed: BT[N][K].
// A, BT, C bf16; bias fp32.  128x128 block tile, BK=32, 256 threads = 4 waves
// (2x2 of 64x64 wave tiles), each wave 4x4 of 16x16x32 MFMA tiles.
template <bool RELU>
__global__ __launch_bounds__(256) void gemm_kernel(const ushort_t* __restrict__ A,
                                                   const ushort_t* __restrict__ BT,
                                                   const float* __restrict__ bias,
                                                   ushort_t* __restrict__ C, int M, int Nn, int K) {
    const int BK = 32, LDA = BK + 8;  // +8 bf16 pad (16B) to break bank strides
    __shared__ ushort_t As[128 * LDA];
    __shared__ ushort_t Bs[128 * LDA];
    int tid = threadIdx.x;
    int lane = tid & 63, w = tid >> 6;
    int wm = (w & 1) * 64, wn = (w >> 1) * 64;
    int bm = blockIdx.y * 128, bn = blockIdx.x * 128;

    f32x4 acc[4][4] = {};

    int c0 = tid, c1 = tid + 256;
    int r0 = c0 >> 2, kc0 = (c0 & 3) * 8;
    int r1 = c1 >> 2, kc1 = (c1 & 3) * 8;

    for (int k0 = 0; k0 < K; k0 += BK) {
        __syncthreads();
        uint4 a0 = *(const uint4*)(A + (size_t)(bm + r0) * K + k0 + kc0);
        uint4 a1 = *(const uint4*)(A + (size_t)(bm + r1) * K + k0 + kc1);
        uint4 b0 = *(const uint4*)(BT + (size_t)(bn + r0) * K + k0 + kc0);
        uint4 b1 = *(const uint4*)(BT + (size_t)(bn + r1) * K + k0 + kc1);
        *(uint4*)(As + r0 * LDA + kc0) = a0;
        *(uint4*)(As + r1 * LDA + kc1) = a1;
        *(uint4*)(Bs + r0 * LDA + kc0) = b0;
        *(uint4*)(Bs + r1 * LDA + kc1) = b1;
        __syncthreads();

        int koff = (lane >> 4) * 8;
        bf16x8 af[4], bfr[4];
#pragma unroll
        for (int i = 0; i < 4; ++i) {
            U4 t;
            t.u = *(const uint4*)(As + (wm + i * 16 + (lane & 15)) * LDA + koff);
            af[i] = t.b;
        }
#pragma unroll
        for (int j = 0; j < 4; ++j) {
            U4 t;
            t.u = *(const uint4*)(Bs + (wn + j * 16 + (lane & 15)) * LDA + koff);
            bfr[j] = t.b;
        }
#pragma unroll
        for (int i = 0; i < 4; ++i)
#pragma unroll
            for (int j = 0; j < 4; ++j)
                acc[i][j] = __builtin_amdgcn_mfma_f32_16x16x32_bf16(af[i], bfr[j], acc[i][j], 0, 0, 0);
    }

    // epilogue: D layout row=(lane>>4)*4+r, col=lane&15 (m91-verified)
#pragma unroll
    for (int i = 0; i < 4; ++i) {
        int row0 = bm + wm + i * 16 + (lane >> 4) * 4;
#pragma unroll
        for (int j = 0; j < 4; ++j) {
            int col = bn + wn + j * 16 + (lane & 15);
            float bv = bias[col];
#pragma unroll
            for (int r = 0; r < 4; ++r) {
                float v = acc[i][j][r] + bv;
                if (RELU) v = fmaxf(v, 0.f);
                C[(size_t)(row0 + r) * Nn + col] = f2b(v);
            }
        }
    }
}

// ---------------------------------------------------------------------------
// 7) out[n,d] = ((h*p+q0) + F) * a2[d] + c2[d], fp32 out.  4 elems/thread.
__global__ void final_kernel(const float* __restrict__ h, const ushort_t* __restrict__ F,
                             const float* __restrict__ p, const float* __restrict__ q0,
                             const float* __restrict__ a2v, const float* __restrict__ c2v,
                             float* __restrict__ out) {
    int idx = (blockIdx.x * blockDim.x + threadIdx.x) * 4;
    int d0 = idx & (DIM - 1);
    float4 hv = *(const float4*)(h + idx);
    ushort_t fv[4];
    *(uint2*)fv = *(const uint2*)(F + idx);
    float4 ov;
    ov.x = ((hv.x * p[d0 + 0] + q0[d0 + 0]) + b2f(fv[0])) * a2v[d0 + 0] + c2v[d0 + 0];
    ov.y = ((hv.y * p[d0 + 1] + q0[d0 + 1]) + b2f(fv[1])) * a2v[d0 + 1] + c2v[d0 + 1];
    ov.z = ((hv.z * p[d0 + 2] + q0[d0 + 2]) + b2f(fv[2])) * a2v[d0 + 2] + c2v[d0 + 2];
    ov.w = ((hv.w * p[d0 + 3] + q0[d0 + 3]) + b2f(fv[3])) * a2v[d0 + 3] + c2v[d0 + 3];
    *(float4*)(out + idx) = ov;
}

// ---------------------------------------------------------------------------
extern "C" void kernel_launch(void* const* d_in, const int* in_sizes, int n_in,
                              void* d_out, int out_size, void* d_ws, size_t ws_size,
                              hipStream_t stream) {
    // inputs (all fp32): 0:A 1:h 2:qw 3:qb 4:kw 5:kb 6:vw 7:vb 8:ow 9:ob
    // 10:f1w 11:f1b 12:f2w 13:f2b 14-17:bn1 g,b,m,v 18-21:bn2 g,b,m,v
    const float* h = (const float*)d_in[1];
    const float* vw = (const float*)d_in[6];
    const float* vb = (const float*)d_in[7];
    const float* ow = (const float*)d_in[8];
    const float* ob = (const float*)d_in[9];
    const float* f1w = (const float*)d_in[10];
    const float* f1b = (const float*)d_in[11];
    const float* f2w = (const float*)d_in[12];
    const float* f2b = (const float*)d_in[13];
    const float* g1 = (const float*)d_in[14];
    const float* b1 = (const float*)d_in[15];
    const float* m1 = (const float*)d_in[16];
    const float* v1 = (const float*)d_in[17];
    const float* g2 = (const float*)d_in[18];
    const float* b2 = (const float*)d_in[19];
    const float* m2 = (const float*)d_in[20];
    const float* v2 = (const float*)d_in[21];
    float* out = (float*)d_out;

    char* ws = (char*)d_ws;
    float* hs = (float*)(ws + 0);              // 512 f32
    float* pC = (float*)(ws + 2048);           // 512 f32
    float* q0C = (float*)(ws + 4096);          // 512 f32
    float* a2C = (float*)(ws + 6144);          // 512 f32
    float* c2C = (float*)(ws + 8192);          // 512 f32
    float* sBuf = (float*)(ws + 10240);        // 512 f32
    float* tBuf = (float*)(ws + 12288);        // 512 f32
    ushort_t* X1 = (ushort_t*)(ws + 16384);    // 8192*512 bf16 (8 MB)
    ushort_t* Z = X1 + (size_t)NROWS * DIM;    // 8192*1024 bf16 (16 MB)
    ushort_t* F = Z + (size_t)NROWS * HID;     // 8192*512 bf16 (8 MB)
    ushort_t* W1T = F + (size_t)NROWS * DIM;   // 1024*512 bf16 (1 MB)
    ushort_t* W2T = W1T + (size_t)HID * DIM;   // 512*1024 bf16 (1 MB)

    hipMemsetAsync(hs, 0, 512 * sizeof(float), stream);
    colsum_kernel<<<64, 256, 0, stream>>>(h, hs);
    matvec_kernel<<<16, 256, 0, stream>>>(hs, vw, vb, 8192.0f, sBuf);
    matvec_kernel<<<16, 256, 0, stream>>>(sBuf, ow, ob, 1.0f, tBuf);
    prep_const_kernel<<<1, 512, 0, stream>>>(tBuf, g1, b1, m1, v1, g2, b2, m2, v2,
                                             pC, q0C, a2C, c2C);
    x1_kernel<<<4096, 256, 0, stream>>>(h, pC, q0C, X1);
    transpose_kernel<<<dim3(32, 16), 256, 0, stream>>>(f1w, W1T, 512, 1024);
    transpose_kernel<<<dim3(16, 32), 256, 0, stream>>>(f2w, W2T, 1024, 512);
    gemm_kernel<true><<<dim3(8, 64), 256, 0, stream>>>(X1, W1T, f1b, Z, NROWS, HID, DIM);
    gemm_kernel<false><<<dim3(4, 64), 256, 0, stream>>>(Z, W2T, f2b, F, NROWS, DIM, HID);
    final_kernel<<<4096, 256, 0, stream>>>(h, F, pC, q0C, a2C, c2C, out);
}